// Round 16
// baseline (439.914 us; speedup 1.0000x reference)
//
#include <hip/hip_runtime.h>
#include <math.h>

#define BATCH 4
#define SEQL 1024
#define DMODEL 256
#define DINNER 512
#define DSTATE 16
#define DTRANK 16
#define NLAYERS 4
#define MTOT (BATCH * SEQL)  // 4096

// LDS swizzle for time-series arrays: slot(t) = (t&63)*17 + (t>>6); max 1086
#define IDX(t) ((((t) & 63) * 17) + ((t) >> 6))

#define LOG2E 1.44269504088896340736f

typedef float v2f __attribute__((ext_vector_type(2)));

static __device__ __forceinline__ v2f pkfma(v2f a, v2f b, v2f c) {
    return __builtin_elementwise_fma(a, b, c);
}
static __device__ __forceinline__ float exp2fast(float x) {
    return __builtin_amdgcn_exp2f(x);
}
static __device__ __forceinline__ float siluf(float x) {
    return x / (1.0f + __expf(-x));
}
static __device__ __forceinline__ float softplusf(float x) {
    return (x > 0.0f) ? (x + __logf(1.0f + __expf(-x))) : __logf(1.0f + __expf(x));
}

// ---------------------------------------------------------------------------
// sgemm3: packed-fp32 SGEMM. C[M,N] = A * B^T; B row-major [N][K].
// AKM: A K-major [K][M]. BSUM: B = Bw + Bw2 (fuses producer's split-K reduce
// into B-staging). BEMB: B computed on the fly = embed(x) (conv3+BN+SiLU),
// N-dim = tokens, K-dim = DMODEL channels — removes the k_embed kernel.
// KSPLIT>1: blockIdx.z K-slice. R13-proven shapes: 64x64/TM4/TN4/BK16.
// ---------------------------------------------------------------------------
template <int BM, int BN, int BK, int TM, int TN, bool AKM, int KTOT, int KSPLIT,
          bool BSUM, bool BEMB>
__global__ __launch_bounds__((BM / TM) * (BN / TN))
void sgemm3(const float* __restrict__ A, int lda,
            const float* __restrict__ Bw, const float* __restrict__ Bw2, int ldb,
            float* __restrict__ C, int ldc, int mstride,
            const float* __restrict__ xe, const float* __restrict__ ew,
            const float* __restrict__ bg, const float* __restrict__ bb,
            const float* __restrict__ bm, const float* __restrict__ bv) {
    constexpr int TX = BN / TN;
    constexpr int TY = BM / TM;
    constexpr int NT = TX * TY;
    static_assert(NT == 256, "expect 256 threads");
    static_assert(TN % 2 == 0, "packed needs even TN");
    constexpr int TN2 = TN / 2;
    constexpr int KS = KTOT / KSPLIT;
    static_assert(KS % BK == 0, "");
    constexpr int NSTEPS = KS / BK;
    constexpr int A4 = BM * BK / 4;
    constexpr int B4 = BN * BK / 4;
    constexpr int APT = (A4 + NT - 1) / NT;
    constexpr int BPT = (B4 + NT - 1) / NT;
    constexpr bool AG = (A4 % NT) != 0;
    constexpr bool BG = (B4 % NT) != 0;

    const int tid = threadIdx.x;
    const int tx = tid % TX;
    const int ty = tid / TX;
    const int m0 = blockIdx.y * BM;
    const int n0 = blockIdx.x * BN;
    const int kt0 = blockIdx.z * KS;

    __shared__ float As[BK][BM + 4];
    __shared__ float Bs[BK][BN + 4];

    v2f acc[TM][TN2] = {};
    float4 ra[APT], rb[BPT];

    auto loadA = [&](int kt) {
#pragma unroll
        for (int u = 0; u < APT; ++u) {
            const int v = tid + u * NT;
            if (!AG || v < A4) {
                if (AKM) {
                    const int kk = v / (BM / 4);
                    const int i4 = v % (BM / 4);
                    ra[u] = *reinterpret_cast<const float4*>(
                        &A[(size_t)(kt + kk) * lda + m0 + i4 * 4]);
                } else {
                    const int i = v / (BK / 4);
                    const int jv = v % (BK / 4);
                    ra[u] = *reinterpret_cast<const float4*>(
                        &A[(size_t)(m0 + i) * lda + kt + jv * 4]);
                }
            }
        }
    };
    auto loadB = [&](int kt) {
#pragma unroll
        for (int u = 0; u < BPT; ++u) {
            const int v = tid + u * NT;
            if (!BG || v < B4) {
                const int i = v / (BK / 4);
                const int jv = v % (BK / 4);
                if (BEMB) {
                    // token t = n0+i ; channels d0..d0+3 = kt + jv*4 ..
                    const int t = n0 + i;
                    const int l = t & 1023;
                    const float x0v = xe[t];
                    const float xm1 = (l > 0) ? xe[t - 1] : 0.0f;
                    const float xp1 = (l < 1023) ? xe[t + 1] : 0.0f;
                    const int d0 = kt + jv * 4;
                    const float4 g4 = *reinterpret_cast<const float4*>(&bg[d0]);
                    const float4 b4 = *reinterpret_cast<const float4*>(&bb[d0]);
                    const float4 m4 = *reinterpret_cast<const float4*>(&bm[d0]);
                    const float4 v4 = *reinterpret_cast<const float4*>(&bv[d0]);
                    const float4 e0 = *reinterpret_cast<const float4*>(&ew[d0 * 3]);
                    const float4 e1 = *reinterpret_cast<const float4*>(&ew[d0 * 3 + 4]);
                    const float4 e2 = *reinterpret_cast<const float4*>(&ew[d0 * 3 + 8]);
                    // channel 0: w = e0.x e0.y e0.z ; ch1: e0.w e1.x e1.y ;
                    // ch2: e1.z e1.w e2.x ; ch3: e2.y e2.z e2.w
                    float c0 = xm1 * e0.x + x0v * e0.y + xp1 * e0.z;
                    float c1 = xm1 * e0.w + x0v * e1.x + xp1 * e1.y;
                    float c2 = xm1 * e1.z + x0v * e1.w + xp1 * e2.x;
                    float c3 = xm1 * e2.y + x0v * e2.z + xp1 * e2.w;
                    c0 = (c0 - m4.x) * (1.0f / sqrtf(v4.x + 1e-5f) * g4.x) + b4.x;
                    c1 = (c1 - m4.y) * (1.0f / sqrtf(v4.y + 1e-5f) * g4.y) + b4.y;
                    c2 = (c2 - m4.z) * (1.0f / sqrtf(v4.z + 1e-5f) * g4.z) + b4.z;
                    c3 = (c3 - m4.w) * (1.0f / sqrtf(v4.w + 1e-5f) * g4.w) + b4.w;
                    rb[u].x = siluf(c0);
                    rb[u].y = siluf(c1);
                    rb[u].z = siluf(c2);
                    rb[u].w = siluf(c3);
                } else {
                    const size_t off = (size_t)(n0 + i) * ldb + kt + jv * 4;
                    rb[u] = *reinterpret_cast<const float4*>(&Bw[off]);
                    if (BSUM) {
                        const float4 t2 = *reinterpret_cast<const float4*>(&Bw2[off]);
                        rb[u].x += t2.x; rb[u].y += t2.y;
                        rb[u].z += t2.z; rb[u].w += t2.w;
                    }
                }
            }
        }
    };
    auto storeAB = [&]() {
#pragma unroll
        for (int u = 0; u < APT; ++u) {
            const int v = tid + u * NT;
            if (!AG || v < A4) {
                if (AKM) {
                    const int kk = v / (BM / 4);
                    const int i4 = v % (BM / 4);
                    *reinterpret_cast<float4*>(&As[kk][i4 * 4]) = ra[u];
                } else {
                    const int i = v / (BK / 4);
                    const int jv = v % (BK / 4);
                    As[jv * 4 + 0][i] = ra[u].x;
                    As[jv * 4 + 1][i] = ra[u].y;
                    As[jv * 4 + 2][i] = ra[u].z;
                    As[jv * 4 + 3][i] = ra[u].w;
                }
            }
        }
#pragma unroll
        for (int u = 0; u < BPT; ++u) {
            const int v = tid + u * NT;
            if (!BG || v < B4) {
                const int i = v / (BK / 4);
                const int jv = v % (BK / 4);
                Bs[jv * 4 + 0][i] = rb[u].x;
                Bs[jv * 4 + 1][i] = rb[u].y;
                Bs[jv * 4 + 2][i] = rb[u].z;
                Bs[jv * 4 + 3][i] = rb[u].w;
            }
        }
    };

    loadA(kt0);
    loadB(kt0);

    for (int s = 0; s < NSTEPS; ++s) {
        storeAB();
        __syncthreads();
        if (s + 1 < NSTEPS) {
            loadA(kt0 + (s + 1) * BK);
            loadB(kt0 + (s + 1) * BK);
        }
#pragma unroll
        for (int k = 0; k < BK; ++k) {
            float a[TM];
            v2f b2[TN2];
#pragma unroll
            for (int i = 0; i < TM; ++i) a[i] = As[k][ty * TM + i];
#pragma unroll
            for (int j = 0; j < TN2; ++j)
                b2[j] = *reinterpret_cast<const v2f*>(&Bs[k][tx * TN + 2 * j]);
#pragma unroll
            for (int i = 0; i < TM; ++i) {
                v2f av;
                av.x = a[i]; av.y = a[i];
#pragma unroll
                for (int j = 0; j < TN2; ++j) acc[i][j] = pkfma(av, b2[j], acc[i][j]);
            }
        }
        __syncthreads();
    }

    float* Cz = C + (size_t)blockIdx.z * mstride;
#pragma unroll
    for (int i = 0; i < TM; ++i) {
        const int m = m0 + ty * TM + i;
#pragma unroll
        for (int j = 0; j < TN2; ++j) {
            *reinterpret_cast<v2f*>(&Cz[(size_t)m * ldc + n0 + tx * TN + 2 * j]) =
                acc[i][j];
        }
    }
}

// ---------------------------------------------------------------------------
// x_proj GEMM with FUSED depthwise conv + SiLU in the A-staging.
// ---------------------------------------------------------------------------
__global__ __launch_bounds__(256)
void sgemm_xp(const float* __restrict__ xzT, const float* __restrict__ cw,
              const float* __restrict__ cb, const float* __restrict__ Bw,
              float* __restrict__ C, int mstride) {
    constexpr int BM = 64, BN = 48, BK = 16, TM = 4, TN = 3;
    constexpr int TX = BN / TN;  // 16
    constexpr int KS = DINNER / 8;   // 64
    constexpr int NSTEPS = KS / BK;  // 4
    constexpr int B4 = BN * BK / 4;  // 192

    const int tid = threadIdx.x;
    const int tx = tid % TX;
    const int ty = tid / TX;
    const int m0 = blockIdx.y * BM;
    const int kt0 = blockIdx.z * KS;

    __shared__ float As[BK][BM + 4];
    __shared__ float Bs[BK][BN + 4];

    float acc[TM][TN] = {};
    float4 ra;
    float4 rb;

    auto loadA = [&](int kt) {
        const int kk = tid >> 4;       // 0..15
        const int i4 = tid & 15;       // 0..15
        const int r = kt + kk;         // channel d
        const float* row = xzT + (size_t)r * MTOT;
        const int t4 = m0 + i4 * 4;
        const float4 xv = *reinterpret_cast<const float4*>(&row[t4]);
        float4 xm = make_float4(0.f, 0.f, 0.f, 0.f);
        if ((t4 & 1023) >= 4) xm = *reinterpret_cast<const float4*>(&row[t4 - 4]);
        const float4 w = *reinterpret_cast<const float4*>(&cw[r * 4]);
        const float bias = cb[r];
        float4 o;
        o.x = fmaf(xv.x, w.w, fmaf(xm.w, w.z, fmaf(xm.z, w.y, fmaf(xm.y, w.x, bias))));
        o.y = fmaf(xv.y, w.w, fmaf(xv.x, w.z, fmaf(xm.w, w.y, fmaf(xm.z, w.x, bias))));
        o.z = fmaf(xv.z, w.w, fmaf(xv.y, w.z, fmaf(xv.x, w.y, fmaf(xm.w, w.x, bias))));
        o.w = fmaf(xv.w, w.w, fmaf(xv.z, w.z, fmaf(xv.y, w.y, fmaf(xv.x, w.x, bias))));
        o.x = siluf(o.x); o.y = siluf(o.y); o.z = siluf(o.z); o.w = siluf(o.w);
        ra = o;
    };
    auto loadB = [&](int kt) {
        if (tid < B4) {
            const int i = tid / (BK / 4);
            const int jv = tid % (BK / 4);
            rb = *reinterpret_cast<const float4*>(
                &Bw[(size_t)i * DINNER + kt + jv * 4]);
        }
    };
    auto storeAB = [&]() {
        const int kk = tid >> 4;
        const int i4 = tid & 15;
        *reinterpret_cast<float4*>(&As[kk][i4 * 4]) = ra;
        if (tid < B4) {
            const int i = tid / (BK / 4);
            const int jv = tid % (BK / 4);
            Bs[jv * 4 + 0][i] = rb.x;
            Bs[jv * 4 + 1][i] = rb.y;
            Bs[jv * 4 + 2][i] = rb.z;
            Bs[jv * 4 + 3][i] = rb.w;
        }
    };

    loadA(kt0);
    loadB(kt0);

    for (int s = 0; s < NSTEPS; ++s) {
        storeAB();
        __syncthreads();
        if (s + 1 < NSTEPS) {
            loadA(kt0 + (s + 1) * BK);
            loadB(kt0 + (s + 1) * BK);
        }
#pragma unroll
        for (int k = 0; k < BK; ++k) {
            float a[TM], b[TN];
#pragma unroll
            for (int i = 0; i < TM; ++i) a[i] = As[k][ty * TM + i];
#pragma unroll
            for (int j = 0; j < TN; ++j) b[j] = Bs[k][tx * TN + j];
#pragma unroll
            for (int i = 0; i < TM; ++i)
#pragma unroll
                for (int j = 0; j < TN; ++j) acc[i][j] = fmaf(a[i], b[j], acc[i][j]);
        }
        __syncthreads();
    }

    float* Cz = C + (size_t)blockIdx.z * mstride;
#pragma unroll
    for (int i = 0; i < TM; ++i) {
        const int m = m0 + ty * TM + i;
#pragma unroll
        for (int j = 0; j < TN; ++j)
            Cz[(size_t)m * 48 + tx * TN + j] = acc[i][j];
    }
}

// ---------------------------------------------------------------------------
// Reduce KS partial outputs (float4-wise): out = sum_z part[z]
// ---------------------------------------------------------------------------
template <int KS>
__global__ __launch_bounds__(512) void k_kred(const float* __restrict__ part,
                                              float* __restrict__ out, int n4) {
    const int i = blockIdx.x * 512 + threadIdx.x;
    if (i >= n4) return;
    const float4* p = reinterpret_cast<const float4*>(part);
    float4 s = p[i];
#pragma unroll
    for (int z = 1; z < KS; ++z) {
        const float4 t = p[i + (size_t)z * n4];
        s.x += t.x; s.y += t.y; s.z += t.z; s.w += t.w;
    }
    reinterpret_cast<float4*>(out)[i] = s;
}

// ---------------------------------------------------------------------------
// Chunked parallel selective scan with FUSED depthwise conv, packed fp32.
// ---------------------------------------------------------------------------
#define CCH 64  // chunks
#define CT 16   // steps per chunk

__global__ __launch_bounds__(256) void k_scan11(
    const float* __restrict__ xdbl, const float* __restrict__ xzT,
    const float* __restrict__ dtw, const float* __restrict__ dtb,
    const float* __restrict__ cw, const float* __restrict__ cb,
    const float* __restrict__ A_log, const float* __restrict__ D_skip,
    float* __restrict__ yT) {
    const int d = blockIdx.x;   // 0..511
    const int b = blockIdx.y;   // 0..3
    const int tid = threadIdx.x;
    const int c = tid >> 2;     // chunk 0..63
    const int nq = tid & 3;     // n-quad 0..3

    __shared__ float dt_s[1088];      // dt during passes; p after Pass B
    __shared__ float u_s[1088];       // du = dt*u
    __shared__ __align__(16) float PSp[CCH][20];
    __shared__ __align__(16) float PSs[CCH][20];

    const int mbase = b * SEQL;
    const float* xrow = xzT + (size_t)d * MTOT + mbase;   // xi row for conv

    const float4 w0 = *reinterpret_cast<const float4*>(&dtw[d * 16 + 0]);
    const float4 w1 = *reinterpret_cast<const float4*>(&dtw[d * 16 + 4]);
    const float4 w2 = *reinterpret_cast<const float4*>(&dtw[d * 16 + 8]);
    const float4 w3 = *reinterpret_cast<const float4*>(&dtw[d * 16 + 12]);
    const float bias = dtb[d];
    const float4 cwv = *reinterpret_cast<const float4*>(&cw[d * 4]);
    const float cbias = cb[d];

    // stage dt (fused dt_proj + softplus) and du = dt*silu(conv(xz))
#pragma unroll
    for (int ph = 0; ph < 4; ++ph) {
        const int t = ph * 256 + tid;
        const float* xr = &xdbl[(size_t)(mbase + t) * 48];
        const float4 a0 = *reinterpret_cast<const float4*>(&xr[0]);
        const float4 a1 = *reinterpret_cast<const float4*>(&xr[4]);
        const float4 a2v = *reinterpret_cast<const float4*>(&xr[8]);
        const float4 a3 = *reinterpret_cast<const float4*>(&xr[12]);
        v2f s2; s2.x = bias; s2.y = 0.0f;
        v2f p, q;
        p.x = a0.x;  p.y = a0.y;  q.x = w0.x;  q.y = w0.y;  s2 = pkfma(p, q, s2);
        p.x = a0.z;  p.y = a0.w;  q.x = w0.z;  q.y = w0.w;  s2 = pkfma(p, q, s2);
        p.x = a1.x;  p.y = a1.y;  q.x = w1.x;  q.y = w1.y;  s2 = pkfma(p, q, s2);
        p.x = a1.z;  p.y = a1.w;  q.x = w1.z;  q.y = w1.w;  s2 = pkfma(p, q, s2);
        p.x = a2v.x; p.y = a2v.y; q.x = w2.x;  q.y = w2.y;  s2 = pkfma(p, q, s2);
        p.x = a2v.z; p.y = a2v.w; q.x = w2.z;  q.y = w2.w;  s2 = pkfma(p, q, s2);
        p.x = a3.x;  p.y = a3.y;  q.x = w3.x;  q.y = w3.y;  s2 = pkfma(p, q, s2);
        p.x = a3.z;  p.y = a3.w;  q.x = w3.z;  q.y = w3.w;  s2 = pkfma(p, q, s2);
        const float dt = softplusf(s2.x + s2.y);
        const float xt  = xrow[t];
        const float xt1 = (t >= 1) ? xrow[t - 1] : 0.0f;
        const float xt2 = (t >= 2) ? xrow[t - 2] : 0.0f;
        const float xt3 = (t >= 3) ? xrow[t - 3] : 0.0f;
        float cv = fmaf(xt, cwv.w, fmaf(xt1, cwv.z,
                   fmaf(xt2, cwv.y, fmaf(xt3, cwv.x, cbias))));
        const float uv = siluf(cv);
        dt_s[IDX(t)] = dt;
        u_s[IDX(t)]  = dt * uv;
    }
    __syncthreads();

    const float4 al = *reinterpret_cast<const float4*>(&A_log[d * DSTATE + nq * 4]);
    v2f a01, a23;
    a01.x = -__expf(al.x) * LOG2E;
    a01.y = -__expf(al.y) * LOG2E;
    a23.x = -__expf(al.z) * LOG2E;
    a23.y = -__expf(al.w) * LOG2E;

    const int t0 = c * CT;
    const int loc_base = (c & 3) * 272 + (c >> 2);

    const float* Bp = &xdbl[(size_t)(mbase + t0) * 48 + DTRANK + nq * 4];
    const float* Cp = Bp + DSTATE;

    // ---- Pass A ----
    float dtsum = 0.0f;
    v2f S01, S23;
    S01.x = S01.y = S23.x = S23.y = 0.0f;
#pragma unroll
    for (int j = 0; j < CT; ++j) {
        const float4 B4 = *reinterpret_cast<const float4*>(&Bp[j * 48]);
        const int loc = j * 17 + loc_base;
        const float dtv = dt_s[loc];
        const float du = u_s[loc];
        dtsum += dtv;
        v2f dd; dd.x = dtv; dd.y = dtv;
        v2f duv; duv.x = du; duv.y = du;
        const v2f t01 = dd * a01;
        const v2f t23 = dd * a23;
        v2f e01, e23;
        e01.x = exp2fast(t01.x); e01.y = exp2fast(t01.y);
        e23.x = exp2fast(t23.x); e23.y = exp2fast(t23.y);
        v2f B01, B23;
        B01.x = B4.x; B01.y = B4.y; B23.x = B4.z; B23.y = B4.w;
        S01 = pkfma(e01, S01, B01 * duv);
        S23 = pkfma(e23, S23, B23 * duv);
    }
    {
        float4 Pq, Sq;
        Pq.x = exp2fast(a01.x * dtsum);
        Pq.y = exp2fast(a01.y * dtsum);
        Pq.z = exp2fast(a23.x * dtsum);
        Pq.w = exp2fast(a23.y * dtsum);
        Sq.x = S01.x; Sq.y = S01.y; Sq.z = S23.x; Sq.w = S23.y;
        *reinterpret_cast<float4*>(&PSp[c][nq * 4]) = Pq;
        *reinterpret_cast<float4*>(&PSs[c][nq * 4]) = Sq;
    }
    __syncthreads();

    // exclusive affine prefix over chunks
    v2f h01, h23;
    h01.x = h01.y = h23.x = h23.y = 0.0f;
    for (int j = 0; j < c; ++j) {
        const float4 qp = *reinterpret_cast<const float4*>(&PSp[j][nq * 4]);
        const float4 qs = *reinterpret_cast<const float4*>(&PSs[j][nq * 4]);
        v2f pp, ss;
        pp.x = qp.x; pp.y = qp.y; ss.x = qs.x; ss.y = qs.y;
        h01 = pkfma(pp, h01, ss);
        pp.x = qp.z; pp.y = qp.w; ss.x = qs.z; ss.y = qs.w;
        h23 = pkfma(pp, h23, ss);
    }

    // ---- Pass B ----
#pragma unroll
    for (int j = 0; j < CT; ++j) {
        const float4 B4 = *reinterpret_cast<const float4*>(&Bp[j * 48]);
        const float4 C4 = *reinterpret_cast<const float4*>(&Cp[j * 48]);
        const int loc = j * 17 + loc_base;
        const float dtv = dt_s[loc];
        const float du = u_s[loc];
        v2f dd; dd.x = dtv; dd.y = dtv;
        v2f duv; duv.x = du; duv.y = du;
        const v2f t01 = dd * a01;
        const v2f t23 = dd * a23;
        v2f e01, e23;
        e01.x = exp2fast(t01.x); e01.y = exp2fast(t01.y);
        e23.x = exp2fast(t23.x); e23.y = exp2fast(t23.y);
        v2f B01, B23;
        B01.x = B4.x; B01.y = B4.y; B23.x = B4.z; B23.y = B4.w;
        h01 = pkfma(e01, h01, B01 * duv);
        h23 = pkfma(e23, h23, B23 * duv);
        v2f C01, C23;
        C01.x = C4.x; C01.y = C4.y; C23.x = C4.z; C23.y = C4.w;
        v2f tt = h01 * C01;
        tt = pkfma(h23, C23, tt);
        float p = tt.x + tt.y;
        p += __shfl_xor(p, 1);
        p += __shfl_xor(p, 2);
        if (nq == 0) dt_s[loc] = p;
    }
    __syncthreads();

    // ---- epilogue ----
    const float Dsk = D_skip[d];
#pragma unroll
    for (int ph = 0; ph < 4; ++ph) {
        const int t = ph * 256 + tid;
        const float xt  = xrow[t];
        const float xt1 = (t >= 1) ? xrow[t - 1] : 0.0f;
        const float xt2 = (t >= 2) ? xrow[t - 2] : 0.0f;
        const float xt3 = (t >= 3) ? xrow[t - 3] : 0.0f;
        float cv = fmaf(xt, cwv.w, fmaf(xt1, cwv.z,
                   fmaf(xt2, cwv.y, fmaf(xt3, cwv.x, cbias))));
        const float uv = siluf(cv);
        const float zv = xzT[(size_t)(DINNER + d) * MTOT + mbase + t];
        yT[(size_t)d * MTOT + mbase + t] = (dt_s[IDX(t)] + uv * Dsk) * siluf(zv);
    }
}

// ---------------------------------------------------------------------------
// Column sums of last layer's out_proj_w: wsum[d] = sum_o w[o,d]
// ---------------------------------------------------------------------------
__global__ void k_wsum(const float* __restrict__ w, float* __restrict__ wsum) {
    const int d = threadIdx.x;  // 0..511
    float s = 0.0f;
    for (int o = 0; o < DMODEL; ++o) s += w[(size_t)o * DINNER + d];
    wsum[d] = s;
}

// ---------------------------------------------------------------------------
// Final: out[m] = sum_d yT[d][m] * wsum[d].  Block: 32 m's, 8 d-groups.
// ---------------------------------------------------------------------------
__global__ __launch_bounds__(256) void k_finalT(const float* __restrict__ yT,
                                                const float* __restrict__ wsum,
                                                float* __restrict__ out) {
    const int tid = threadIdx.x;
    const int dg = tid >> 5;       // 0..7
    const int ml = tid & 31;
    const int m = blockIdx.x * 32 + ml;
    float acc = 0.0f;
    const int dbase = dg * 64;
#pragma unroll 8
    for (int dd = 0; dd < 64; ++dd)
        acc = fmaf(yT[(size_t)(dbase + dd) * MTOT + m], wsum[dbase + dd], acc);
    __shared__ float red[8][33];
    red[dg][ml] = acc;
    __syncthreads();
    if (dg == 0) {
        float s = 0.0f;
#pragma unroll
        for (int g = 0; g < 8; ++g) s += red[g][ml];
        out[m] = s;
    }
}

// ---------------------------------------------------------------------------
extern "C" void kernel_launch(void* const* d_in, const int* in_sizes, int n_in,
                              void* d_out, int out_size, void* d_ws, size_t ws_size,
                              hipStream_t stream) {
    const float* x        = (const float*)d_in[0];
    const float* emb_w    = (const float*)d_in[2];
    const float* bn_gamma = (const float*)d_in[3];
    const float* bn_beta  = (const float*)d_in[4];
    const float* bn_mean  = (const float*)d_in[5];
    const float* bn_var   = (const float*)d_in[6];
    const float* in_proj_w  = (const float*)d_in[7];
    const float* conv_w     = (const float*)d_in[8];
    const float* conv_b     = (const float*)d_in[9];
    const float* x_proj_w   = (const float*)d_in[10];
    const float* dt_proj_w  = (const float*)d_in[11];
    const float* dt_proj_b  = (const float*)d_in[12];
    const float* A_log      = (const float*)d_in[13];
    const float* D_skip     = (const float*)d_in[14];
    const float* out_proj_w = (const float*)d_in[15];
    float* out = (float*)d_out;
    float* ws = (float*)d_ws;

    // workspace layout (floats)
    float* h     = ws;                              // (unused; kept for layout)
    float* xzT   = h + (size_t)MTOT * DMODEL;       // 4,194,304
    float* partO = xzT + (size_t)1024 * MTOT;       // 2,097,152
    float* xdbl  = partO + (size_t)2 * MTOT * DMODEL;  // 196,608
    float* yT    = xdbl + (size_t)MTOT * 48;        // 2,097,152
    float* wsum  = yT + (size_t)DINNER * MTOT;      // 512
    float* partX = yT;   // x_proj split-K partials (8 x 4096 x 48, fits)

    for (int i = 0; i < NLAYERS; ++i) {
        const float* in_w  = in_proj_w + (size_t)i * 2 * DINNER * DMODEL;
        const float* cw    = conv_w + (size_t)i * DINNER * 4;
        const float* cb    = conv_b + (size_t)i * DINNER;
        const float* xp_w  = x_proj_w + (size_t)i * 48 * DINNER;
        const float* dtp_w = dt_proj_w + (size_t)i * DINNER * DTRANK;
        const float* dtp_b = dt_proj_b + (size_t)i * DINNER;
        const float* Al    = A_log + (size_t)i * DINNER * DSTATE;
        const float* Dsk   = D_skip + (size_t)i * DINNER;
        const float* o_w   = out_proj_w + (size_t)i * DMODEL * DINNER;

        // xzT[1024][4096] = in_w @ B^T ; 64x64/TM4/TN4/BK16 (R13 proven).
        // i==0: B = embed(x) computed in staging (k_embed dispatch removed).
        // i>0 : B = partO[0] + partO[1] (out_proj split-K reduce fused).
        if (i == 0) {
            sgemm3<64, 64, 16, 4, 4, false, DMODEL, 1, false, true>
                <<<dim3(MTOT / 64, 1024 / 64, 1), 256, 0, stream>>>(
                    in_w, DMODEL, nullptr, nullptr, DMODEL, xzT, MTOT, 0,
                    x, emb_w, bn_gamma, bn_beta, bn_mean, bn_var);
        } else {
            sgemm3<64, 64, 16, 4, 4, false, DMODEL, 1, true, false>
                <<<dim3(MTOT / 64, 1024 / 64, 1), 256, 0, stream>>>(
                    in_w, DMODEL, partO, partO + (size_t)MTOT * DMODEL, DMODEL,
                    xzT, MTOT, 0,
                    nullptr, nullptr, nullptr, nullptr, nullptr, nullptr);
        }

        // x_proj with fused conv: partX[z][4096][48], split-K=8, then reduce
        sgemm_xp<<<dim3(1, MTOT / 64, 8), 256, 0, stream>>>(
            xzT, cw, cb, xp_w, partX, MTOT * 48);
        k_kred<8><<<(MTOT * 48 / 4 + 511) / 512, 512, 0, stream>>>(
            partX, xdbl, MTOT * 48 / 4);

        // scan (fused conv + dt_proj + epilogue) -> yT
        k_scan11<<<dim3(DINNER, BATCH), 256, 0, stream>>>(
            xdbl, xzT, dtp_w, dtp_b, cw, cb, Al, Dsk, yT);

        if (i < NLAYERS - 1) {
            // out_proj: 64x32 tile, BK=16, split-K=2 -> 1024 blocks (4/CU)
            sgemm3<64, 32, 16, 4, 2, true, DINNER, 2, false, false>
                <<<dim3(DMODEL / 32, MTOT / 64, 2), 256, 0, stream>>>(
                    yT, MTOT, o_w, o_w, DINNER, partO, DMODEL, MTOT * DMODEL,
                    nullptr, nullptr, nullptr, nullptr, nullptr, nullptr);
        } else {
            k_wsum<<<1, DINNER, 0, stream>>>(o_w, wsum);
            k_finalT<<<MTOT / 32, 256, 0, stream>>>(yT, wsum, out);
        }
    }
}

// Round 17
// 420.243 us; speedup vs baseline: 1.0468x; 1.0468x over previous
//
#include <hip/hip_runtime.h>
#include <math.h>

#define BATCH 4
#define SEQL 1024
#define DMODEL 256
#define DINNER 512
#define DSTATE 16
#define DTRANK 16
#define NLAYERS 4
#define MTOT (BATCH * SEQL)  // 4096

// LDS swizzle for time-series arrays: slot(t) = (t&63)*17 + (t>>6); max 1086
#define IDX(t) ((((t) & 63) * 17) + ((t) >> 6))

#define LOG2E 1.44269504088896340736f

typedef float v2f __attribute__((ext_vector_type(2)));

static __device__ __forceinline__ v2f pkfma(v2f a, v2f b, v2f c) {
    return __builtin_elementwise_fma(a, b, c);
}
static __device__ __forceinline__ float exp2fast(float x) {
    return __builtin_amdgcn_exp2f(x);
}
static __device__ __forceinline__ float siluf(float x) {
    return x / (1.0f + __expf(-x));
}
static __device__ __forceinline__ float softplusf(float x) {
    return (x > 0.0f) ? (x + __logf(1.0f + __expf(-x))) : __logf(1.0f + __expf(x));
}

// ---------------------------------------------------------------------------
// Embedding conv (k=3, SAME) + BatchNorm + SiLU  ->  h (B*L, DMODEL) row-major
// (R16's fusion of this into in_proj staging cost 16x recompute — reverted.)
// ---------------------------------------------------------------------------
__global__ void k_embed(const float* __restrict__ x, const float* __restrict__ emb_w,
                        const float* __restrict__ gamma, const float* __restrict__ beta,
                        const float* __restrict__ mean, const float* __restrict__ var,
                        float* __restrict__ h) {
    const int m = blockIdx.x;             // b*L + l
    const int d = threadIdx.x;            // 0..255
    const int b = m >> 10;
    const int l = m & 1023;
    const float xm1 = (l > 0)    ? x[b * SEQL + l - 1] : 0.0f;
    const float x0  =              x[b * SEQL + l];
    const float xp1 = (l < 1023) ? x[b * SEQL + l + 1] : 0.0f;
    float c = xm1 * emb_w[d * 3 + 0] + x0 * emb_w[d * 3 + 1] + xp1 * emb_w[d * 3 + 2];
    const float inv = 1.0f / sqrtf(var[d] + 1e-5f);
    c = (c - mean[d]) * (inv * gamma[d]) + beta[d];
    h[(size_t)m * DMODEL + d] = siluf(c);
}

// ---------------------------------------------------------------------------
// sgemm3: packed-fp32 SGEMM. C[M,N] = A * B^T; B row-major [N][K].
// AKM: A K-major [K][M]. BSUM: B = Bw + Bw2 (fuses producer's split-K reduce
// into this consumer's B-staging). KSPLIT>1: blockIdx.z K-slice.
// R13-proven local optimum: 64x64/TM4/TN4/BK16, VGPR=32 no-spill, 4 blk/CU.
// (R14 TM=8 spilled; R15 BK=32 lost prefetch depth; R16 BEMB recomputed 16x.)
// ---------------------------------------------------------------------------
template <int BM, int BN, int BK, int TM, int TN, bool AKM, int KTOT, int KSPLIT,
          bool BSUM>
__global__ __launch_bounds__((BM / TM) * (BN / TN))
void sgemm3(const float* __restrict__ A, int lda,
            const float* __restrict__ Bw, const float* __restrict__ Bw2, int ldb,
            float* __restrict__ C, int ldc, int mstride) {
    constexpr int TX = BN / TN;
    constexpr int TY = BM / TM;
    constexpr int NT = TX * TY;
    static_assert(NT == 256, "expect 256 threads");
    static_assert(TN % 2 == 0, "packed needs even TN");
    constexpr int TN2 = TN / 2;
    constexpr int KS = KTOT / KSPLIT;
    static_assert(KS % BK == 0, "");
    constexpr int NSTEPS = KS / BK;
    constexpr int A4 = BM * BK / 4;
    constexpr int B4 = BN * BK / 4;
    constexpr int APT = (A4 + NT - 1) / NT;
    constexpr int BPT = (B4 + NT - 1) / NT;
    constexpr bool AG = (A4 % NT) != 0;
    constexpr bool BG = (B4 % NT) != 0;

    const int tid = threadIdx.x;
    const int tx = tid % TX;
    const int ty = tid / TX;
    const int m0 = blockIdx.y * BM;
    const int n0 = blockIdx.x * BN;
    const int kt0 = blockIdx.z * KS;

    __shared__ float As[BK][BM + 4];
    __shared__ float Bs[BK][BN + 4];

    v2f acc[TM][TN2] = {};
    float4 ra[APT], rb[BPT];

    auto loadA = [&](int kt) {
#pragma unroll
        for (int u = 0; u < APT; ++u) {
            const int v = tid + u * NT;
            if (!AG || v < A4) {
                if (AKM) {
                    const int kk = v / (BM / 4);
                    const int i4 = v % (BM / 4);
                    ra[u] = *reinterpret_cast<const float4*>(
                        &A[(size_t)(kt + kk) * lda + m0 + i4 * 4]);
                } else {
                    const int i = v / (BK / 4);
                    const int jv = v % (BK / 4);
                    ra[u] = *reinterpret_cast<const float4*>(
                        &A[(size_t)(m0 + i) * lda + kt + jv * 4]);
                }
            }
        }
    };
    auto loadB = [&](int kt) {
#pragma unroll
        for (int u = 0; u < BPT; ++u) {
            const int v = tid + u * NT;
            if (!BG || v < B4) {
                const int i = v / (BK / 4);
                const int jv = v % (BK / 4);
                const size_t off = (size_t)(n0 + i) * ldb + kt + jv * 4;
                rb[u] = *reinterpret_cast<const float4*>(&Bw[off]);
                if (BSUM) {
                    const float4 t2 = *reinterpret_cast<const float4*>(&Bw2[off]);
                    rb[u].x += t2.x; rb[u].y += t2.y;
                    rb[u].z += t2.z; rb[u].w += t2.w;
                }
            }
        }
    };
    auto storeAB = [&]() {
#pragma unroll
        for (int u = 0; u < APT; ++u) {
            const int v = tid + u * NT;
            if (!AG || v < A4) {
                if (AKM) {
                    const int kk = v / (BM / 4);
                    const int i4 = v % (BM / 4);
                    *reinterpret_cast<float4*>(&As[kk][i4 * 4]) = ra[u];
                } else {
                    const int i = v / (BK / 4);
                    const int jv = v % (BK / 4);
                    As[jv * 4 + 0][i] = ra[u].x;
                    As[jv * 4 + 1][i] = ra[u].y;
                    As[jv * 4 + 2][i] = ra[u].z;
                    As[jv * 4 + 3][i] = ra[u].w;
                }
            }
        }
#pragma unroll
        for (int u = 0; u < BPT; ++u) {
            const int v = tid + u * NT;
            if (!BG || v < B4) {
                const int i = v / (BK / 4);
                const int jv = v % (BK / 4);
                Bs[jv * 4 + 0][i] = rb[u].x;
                Bs[jv * 4 + 1][i] = rb[u].y;
                Bs[jv * 4 + 2][i] = rb[u].z;
                Bs[jv * 4 + 3][i] = rb[u].w;
            }
        }
    };

    loadA(kt0);
    loadB(kt0);

    for (int s = 0; s < NSTEPS; ++s) {
        storeAB();
        __syncthreads();
        if (s + 1 < NSTEPS) {
            loadA(kt0 + (s + 1) * BK);
            loadB(kt0 + (s + 1) * BK);
        }
#pragma unroll
        for (int k = 0; k < BK; ++k) {
            float a[TM];
            v2f b2[TN2];
#pragma unroll
            for (int i = 0; i < TM; ++i) a[i] = As[k][ty * TM + i];
#pragma unroll
            for (int j = 0; j < TN2; ++j)
                b2[j] = *reinterpret_cast<const v2f*>(&Bs[k][tx * TN + 2 * j]);
#pragma unroll
            for (int i = 0; i < TM; ++i) {
                v2f av;
                av.x = a[i]; av.y = a[i];
#pragma unroll
                for (int j = 0; j < TN2; ++j) acc[i][j] = pkfma(av, b2[j], acc[i][j]);
            }
        }
        __syncthreads();
    }

    float* Cz = C + (size_t)blockIdx.z * mstride;
#pragma unroll
    for (int i = 0; i < TM; ++i) {
        const int m = m0 + ty * TM + i;
#pragma unroll
        for (int j = 0; j < TN2; ++j) {
            *reinterpret_cast<v2f*>(&Cz[(size_t)m * ldc + n0 + tx * TN + 2 * j]) =
                acc[i][j];
        }
    }
}

// ---------------------------------------------------------------------------
// x_proj GEMM with FUSED depthwise conv + SiLU in the A-staging.
// ---------------------------------------------------------------------------
__global__ __launch_bounds__(256)
void sgemm_xp(const float* __restrict__ xzT, const float* __restrict__ cw,
              const float* __restrict__ cb, const float* __restrict__ Bw,
              float* __restrict__ C, int mstride) {
    constexpr int BM = 64, BN = 48, BK = 16, TM = 4, TN = 3;
    constexpr int TX = BN / TN;  // 16
    constexpr int KS = DINNER / 8;   // 64
    constexpr int NSTEPS = KS / BK;  // 4
    constexpr int B4 = BN * BK / 4;  // 192

    const int tid = threadIdx.x;
    const int tx = tid % TX;
    const int ty = tid / TX;
    const int m0 = blockIdx.y * BM;
    const int kt0 = blockIdx.z * KS;

    __shared__ float As[BK][BM + 4];
    __shared__ float Bs[BK][BN + 4];

    float acc[TM][TN] = {};
    float4 ra;
    float4 rb;

    auto loadA = [&](int kt) {
        const int kk = tid >> 4;       // 0..15
        const int i4 = tid & 15;       // 0..15
        const int r = kt + kk;         // channel d
        const float* row = xzT + (size_t)r * MTOT;
        const int t4 = m0 + i4 * 4;
        const float4 xv = *reinterpret_cast<const float4*>(&row[t4]);
        float4 xm = make_float4(0.f, 0.f, 0.f, 0.f);
        if ((t4 & 1023) >= 4) xm = *reinterpret_cast<const float4*>(&row[t4 - 4]);
        const float4 w = *reinterpret_cast<const float4*>(&cw[r * 4]);
        const float bias = cb[r];
        float4 o;
        o.x = fmaf(xv.x, w.w, fmaf(xm.w, w.z, fmaf(xm.z, w.y, fmaf(xm.y, w.x, bias))));
        o.y = fmaf(xv.y, w.w, fmaf(xv.x, w.z, fmaf(xm.w, w.y, fmaf(xm.z, w.x, bias))));
        o.z = fmaf(xv.z, w.w, fmaf(xv.y, w.z, fmaf(xv.x, w.y, fmaf(xm.w, w.x, bias))));
        o.w = fmaf(xv.w, w.w, fmaf(xv.z, w.z, fmaf(xv.y, w.y, fmaf(xv.x, w.x, bias))));
        o.x = siluf(o.x); o.y = siluf(o.y); o.z = siluf(o.z); o.w = siluf(o.w);
        ra = o;
    };
    auto loadB = [&](int kt) {
        if (tid < B4) {
            const int i = tid / (BK / 4);
            const int jv = tid % (BK / 4);
            rb = *reinterpret_cast<const float4*>(
                &Bw[(size_t)i * DINNER + kt + jv * 4]);
        }
    };
    auto storeAB = [&]() {
        const int kk = tid >> 4;
        const int i4 = tid & 15;
        *reinterpret_cast<float4*>(&As[kk][i4 * 4]) = ra;
        if (tid < B4) {
            const int i = tid / (BK / 4);
            const int jv = tid % (BK / 4);
            Bs[jv * 4 + 0][i] = rb.x;
            Bs[jv * 4 + 1][i] = rb.y;
            Bs[jv * 4 + 2][i] = rb.z;
            Bs[jv * 4 + 3][i] = rb.w;
        }
    };

    loadA(kt0);
    loadB(kt0);

    for (int s = 0; s < NSTEPS; ++s) {
        storeAB();
        __syncthreads();
        if (s + 1 < NSTEPS) {
            loadA(kt0 + (s + 1) * BK);
            loadB(kt0 + (s + 1) * BK);
        }
#pragma unroll
        for (int k = 0; k < BK; ++k) {
            float a[TM], b[TN];
#pragma unroll
            for (int i = 0; i < TM; ++i) a[i] = As[k][ty * TM + i];
#pragma unroll
            for (int j = 0; j < TN; ++j) b[j] = Bs[k][tx * TN + j];
#pragma unroll
            for (int i = 0; i < TM; ++i)
#pragma unroll
                for (int j = 0; j < TN; ++j) acc[i][j] = fmaf(a[i], b[j], acc[i][j]);
        }
        __syncthreads();
    }

    float* Cz = C + (size_t)blockIdx.z * mstride;
#pragma unroll
    for (int i = 0; i < TM; ++i) {
        const int m = m0 + ty * TM + i;
#pragma unroll
        for (int j = 0; j < TN; ++j)
            Cz[(size_t)m * 48 + tx * TN + j] = acc[i][j];
    }
}

// ---------------------------------------------------------------------------
// Reduce KS partial outputs (float4-wise): out = sum_z part[z]
// ---------------------------------------------------------------------------
template <int KS>
__global__ __launch_bounds__(512) void k_kred(const float* __restrict__ part,
                                              float* __restrict__ out, int n4) {
    const int i = blockIdx.x * 512 + threadIdx.x;
    if (i >= n4) return;
    const float4* p = reinterpret_cast<const float4*>(part);
    float4 s = p[i];
#pragma unroll
    for (int z = 1; z < KS; ++z) {
        const float4 t = p[i + (size_t)z * n4];
        s.x += t.x; s.y += t.y; s.z += t.z; s.w += t.w;
    }
    reinterpret_cast<float4*>(out)[i] = s;
}

// ---------------------------------------------------------------------------
// Chunked parallel selective scan with FUSED depthwise conv, packed fp32.
// ---------------------------------------------------------------------------
#define CCH 64  // chunks
#define CT 16   // steps per chunk

__global__ __launch_bounds__(256) void k_scan11(
    const float* __restrict__ xdbl, const float* __restrict__ xzT,
    const float* __restrict__ dtw, const float* __restrict__ dtb,
    const float* __restrict__ cw, const float* __restrict__ cb,
    const float* __restrict__ A_log, const float* __restrict__ D_skip,
    float* __restrict__ yT) {
    const int d = blockIdx.x;   // 0..511
    const int b = blockIdx.y;   // 0..3
    const int tid = threadIdx.x;
    const int c = tid >> 2;     // chunk 0..63
    const int nq = tid & 3;     // n-quad 0..3

    __shared__ float dt_s[1088];      // dt during passes; p after Pass B
    __shared__ float u_s[1088];       // du = dt*u
    __shared__ __align__(16) float PSp[CCH][20];
    __shared__ __align__(16) float PSs[CCH][20];

    const int mbase = b * SEQL;
    const float* xrow = xzT + (size_t)d * MTOT + mbase;   // xi row for conv

    const float4 w0 = *reinterpret_cast<const float4*>(&dtw[d * 16 + 0]);
    const float4 w1 = *reinterpret_cast<const float4*>(&dtw[d * 16 + 4]);
    const float4 w2 = *reinterpret_cast<const float4*>(&dtw[d * 16 + 8]);
    const float4 w3 = *reinterpret_cast<const float4*>(&dtw[d * 16 + 12]);
    const float bias = dtb[d];
    const float4 cwv = *reinterpret_cast<const float4*>(&cw[d * 4]);
    const float cbias = cb[d];

    // stage dt (fused dt_proj + softplus) and du = dt*silu(conv(xz))
#pragma unroll
    for (int ph = 0; ph < 4; ++ph) {
        const int t = ph * 256 + tid;
        const float* xr = &xdbl[(size_t)(mbase + t) * 48];
        const float4 a0 = *reinterpret_cast<const float4*>(&xr[0]);
        const float4 a1 = *reinterpret_cast<const float4*>(&xr[4]);
        const float4 a2v = *reinterpret_cast<const float4*>(&xr[8]);
        const float4 a3 = *reinterpret_cast<const float4*>(&xr[12]);
        v2f s2; s2.x = bias; s2.y = 0.0f;
        v2f p, q;
        p.x = a0.x;  p.y = a0.y;  q.x = w0.x;  q.y = w0.y;  s2 = pkfma(p, q, s2);
        p.x = a0.z;  p.y = a0.w;  q.x = w0.z;  q.y = w0.w;  s2 = pkfma(p, q, s2);
        p.x = a1.x;  p.y = a1.y;  q.x = w1.x;  q.y = w1.y;  s2 = pkfma(p, q, s2);
        p.x = a1.z;  p.y = a1.w;  q.x = w1.z;  q.y = w1.w;  s2 = pkfma(p, q, s2);
        p.x = a2v.x; p.y = a2v.y; q.x = w2.x;  q.y = w2.y;  s2 = pkfma(p, q, s2);
        p.x = a2v.z; p.y = a2v.w; q.x = w2.z;  q.y = w2.w;  s2 = pkfma(p, q, s2);
        p.x = a3.x;  p.y = a3.y;  q.x = w3.x;  q.y = w3.y;  s2 = pkfma(p, q, s2);
        p.x = a3.z;  p.y = a3.w;  q.x = w3.z;  q.y = w3.w;  s2 = pkfma(p, q, s2);
        const float dt = softplusf(s2.x + s2.y);
        const float xt  = xrow[t];
        const float xt1 = (t >= 1) ? xrow[t - 1] : 0.0f;
        const float xt2 = (t >= 2) ? xrow[t - 2] : 0.0f;
        const float xt3 = (t >= 3) ? xrow[t - 3] : 0.0f;
        float cv = fmaf(xt, cwv.w, fmaf(xt1, cwv.z,
                   fmaf(xt2, cwv.y, fmaf(xt3, cwv.x, cbias))));
        const float uv = siluf(cv);
        dt_s[IDX(t)] = dt;
        u_s[IDX(t)]  = dt * uv;
    }
    __syncthreads();

    const float4 al = *reinterpret_cast<const float4*>(&A_log[d * DSTATE + nq * 4]);
    v2f a01, a23;
    a01.x = -__expf(al.x) * LOG2E;
    a01.y = -__expf(al.y) * LOG2E;
    a23.x = -__expf(al.z) * LOG2E;
    a23.y = -__expf(al.w) * LOG2E;

    const int t0 = c * CT;
    const int loc_base = (c & 3) * 272 + (c >> 2);

    const float* Bp = &xdbl[(size_t)(mbase + t0) * 48 + DTRANK + nq * 4];
    const float* Cp = Bp + DSTATE;

    // ---- Pass A ----
    float dtsum = 0.0f;
    v2f S01, S23;
    S01.x = S01.y = S23.x = S23.y = 0.0f;
#pragma unroll
    for (int j = 0; j < CT; ++j) {
        const float4 B4 = *reinterpret_cast<const float4*>(&Bp[j * 48]);
        const int loc = j * 17 + loc_base;
        const float dtv = dt_s[loc];
        const float du = u_s[loc];
        dtsum += dtv;
        v2f dd; dd.x = dtv; dd.y = dtv;
        v2f duv; duv.x = du; duv.y = du;
        const v2f t01 = dd * a01;
        const v2f t23 = dd * a23;
        v2f e01, e23;
        e01.x = exp2fast(t01.x); e01.y = exp2fast(t01.y);
        e23.x = exp2fast(t23.x); e23.y = exp2fast(t23.y);
        v2f B01, B23;
        B01.x = B4.x; B01.y = B4.y; B23.x = B4.z; B23.y = B4.w;
        S01 = pkfma(e01, S01, B01 * duv);
        S23 = pkfma(e23, S23, B23 * duv);
    }
    {
        float4 Pq, Sq;
        Pq.x = exp2fast(a01.x * dtsum);
        Pq.y = exp2fast(a01.y * dtsum);
        Pq.z = exp2fast(a23.x * dtsum);
        Pq.w = exp2fast(a23.y * dtsum);
        Sq.x = S01.x; Sq.y = S01.y; Sq.z = S23.x; Sq.w = S23.y;
        *reinterpret_cast<float4*>(&PSp[c][nq * 4]) = Pq;
        *reinterpret_cast<float4*>(&PSs[c][nq * 4]) = Sq;
    }
    __syncthreads();

    // exclusive affine prefix over chunks
    v2f h01, h23;
    h01.x = h01.y = h23.x = h23.y = 0.0f;
    for (int j = 0; j < c; ++j) {
        const float4 qp = *reinterpret_cast<const float4*>(&PSp[j][nq * 4]);
        const float4 qs = *reinterpret_cast<const float4*>(&PSs[j][nq * 4]);
        v2f pp, ss;
        pp.x = qp.x; pp.y = qp.y; ss.x = qs.x; ss.y = qs.y;
        h01 = pkfma(pp, h01, ss);
        pp.x = qp.z; pp.y = qp.w; ss.x = qs.z; ss.y = qs.w;
        h23 = pkfma(pp, h23, ss);
    }

    // ---- Pass B ----
#pragma unroll
    for (int j = 0; j < CT; ++j) {
        const float4 B4 = *reinterpret_cast<const float4*>(&Bp[j * 48]);
        const float4 C4 = *reinterpret_cast<const float4*>(&Cp[j * 48]);
        const int loc = j * 17 + loc_base;
        const float dtv = dt_s[loc];
        const float du = u_s[loc];
        v2f dd; dd.x = dtv; dd.y = dtv;
        v2f duv; duv.x = du; duv.y = du;
        const v2f t01 = dd * a01;
        const v2f t23 = dd * a23;
        v2f e01, e23;
        e01.x = exp2fast(t01.x); e01.y = exp2fast(t01.y);
        e23.x = exp2fast(t23.x); e23.y = exp2fast(t23.y);
        v2f B01, B23;
        B01.x = B4.x; B01.y = B4.y; B23.x = B4.z; B23.y = B4.w;
        h01 = pkfma(e01, h01, B01 * duv);
        h23 = pkfma(e23, h23, B23 * duv);
        v2f C01, C23;
        C01.x = C4.x; C01.y = C4.y; C23.x = C4.z; C23.y = C4.w;
        v2f tt = h01 * C01;
        tt = pkfma(h23, C23, tt);
        float p = tt.x + tt.y;
        p += __shfl_xor(p, 1);
        p += __shfl_xor(p, 2);
        if (nq == 0) dt_s[loc] = p;
    }
    __syncthreads();

    // ---- epilogue ----
    const float Dsk = D_skip[d];
#pragma unroll
    for (int ph = 0; ph < 4; ++ph) {
        const int t = ph * 256 + tid;
        const float xt  = xrow[t];
        const float xt1 = (t >= 1) ? xrow[t - 1] : 0.0f;
        const float xt2 = (t >= 2) ? xrow[t - 2] : 0.0f;
        const float xt3 = (t >= 3) ? xrow[t - 3] : 0.0f;
        float cv = fmaf(xt, cwv.w, fmaf(xt1, cwv.z,
                   fmaf(xt2, cwv.y, fmaf(xt3, cwv.x, cbias))));
        const float uv = siluf(cv);
        const float zv = xzT[(size_t)(DINNER + d) * MTOT + mbase + t];
        yT[(size_t)d * MTOT + mbase + t] = (dt_s[IDX(t)] + uv * Dsk) * siluf(zv);
    }
}

// ---------------------------------------------------------------------------
// Column sums of last layer's out_proj_w: wsum[d] = sum_o w[o,d]
// ---------------------------------------------------------------------------
__global__ void k_wsum(const float* __restrict__ w, float* __restrict__ wsum) {
    const int d = threadIdx.x;  // 0..511
    float s = 0.0f;
    for (int o = 0; o < DMODEL; ++o) s += w[(size_t)o * DINNER + d];
    wsum[d] = s;
}

// ---------------------------------------------------------------------------
// Final: out[m] = sum_d yT[d][m] * wsum[d].  Block: 32 m's, 8 d-groups.
// ---------------------------------------------------------------------------
__global__ __launch_bounds__(256) void k_finalT(const float* __restrict__ yT,
                                                const float* __restrict__ wsum,
                                                float* __restrict__ out) {
    const int tid = threadIdx.x;
    const int dg = tid >> 5;       // 0..7
    const int ml = tid & 31;
    const int m = blockIdx.x * 32 + ml;
    float acc = 0.0f;
    const int dbase = dg * 64;
#pragma unroll 8
    for (int dd = 0; dd < 64; ++dd)
        acc = fmaf(yT[(size_t)(dbase + dd) * MTOT + m], wsum[dbase + dd], acc);
    __shared__ float red[8][33];
    red[dg][ml] = acc;
    __syncthreads();
    if (dg == 0) {
        float s = 0.0f;
#pragma unroll
        for (int g = 0; g < 8; ++g) s += red[g][ml];
        out[m] = s;
    }
}

// ---------------------------------------------------------------------------
extern "C" void kernel_launch(void* const* d_in, const int* in_sizes, int n_in,
                              void* d_out, int out_size, void* d_ws, size_t ws_size,
                              hipStream_t stream) {
    const float* x        = (const float*)d_in[0];
    const float* emb_w    = (const float*)d_in[2];
    const float* bn_gamma = (const float*)d_in[3];
    const float* bn_beta  = (const float*)d_in[4];
    const float* bn_mean  = (const float*)d_in[5];
    const float* bn_var   = (const float*)d_in[6];
    const float* in_proj_w  = (const float*)d_in[7];
    const float* conv_w     = (const float*)d_in[8];
    const float* conv_b     = (const float*)d_in[9];
    const float* x_proj_w   = (const float*)d_in[10];
    const float* dt_proj_w  = (const float*)d_in[11];
    const float* dt_proj_b  = (const float*)d_in[12];
    const float* A_log      = (const float*)d_in[13];
    const float* D_skip     = (const float*)d_in[14];
    const float* out_proj_w = (const float*)d_in[15];
    float* out = (float*)d_out;
    float* ws = (float*)d_ws;

    // workspace layout (floats)
    float* h     = ws;                              // 1,048,576
    float* xzT   = h + (size_t)MTOT * DMODEL;       // 4,194,304
    float* partO = xzT + (size_t)1024 * MTOT;       // 2,097,152
    float* xdbl  = partO + (size_t)2 * MTOT * DMODEL;  // 196,608
    float* yT    = xdbl + (size_t)MTOT * 48;        // 2,097,152
    float* wsum  = yT + (size_t)DINNER * MTOT;      // 512
    float* partX = yT;   // x_proj split-K partials (8 x 4096 x 48, fits)

    k_embed<<<MTOT, DMODEL, 0, stream>>>(x, emb_w, bn_gamma, bn_beta, bn_mean, bn_var, h);

    for (int i = 0; i < NLAYERS; ++i) {
        const float* in_w  = in_proj_w + (size_t)i * 2 * DINNER * DMODEL;
        const float* cw    = conv_w + (size_t)i * DINNER * 4;
        const float* cb    = conv_b + (size_t)i * DINNER;
        const float* xp_w  = x_proj_w + (size_t)i * 48 * DINNER;
        const float* dtp_w = dt_proj_w + (size_t)i * DINNER * DTRANK;
        const float* dtp_b = dt_proj_b + (size_t)i * DINNER;
        const float* Al    = A_log + (size_t)i * DINNER * DSTATE;
        const float* Dsk   = D_skip + (size_t)i * DINNER;
        const float* o_w   = out_proj_w + (size_t)i * DMODEL * DINNER;

        // xzT[1024][4096] = in_w @ h^T ; 64x64/TM4/TN4/BK16 (R13 proven)
        if (i == 0) {
            sgemm3<64, 64, 16, 4, 4, false, DMODEL, 1, false>
                <<<dim3(MTOT / 64, 1024 / 64, 1), 256, 0, stream>>>(
                    in_w, DMODEL, h, h, DMODEL, xzT, MTOT, 0);
        } else {
            sgemm3<64, 64, 16, 4, 4, false, DMODEL, 1, true>
                <<<dim3(MTOT / 64, 1024 / 64, 1), 256, 0, stream>>>(
                    in_w, DMODEL, partO, partO + (size_t)MTOT * DMODEL, DMODEL,
                    xzT, MTOT, 0);
        }

        // x_proj with fused conv: partX[z][4096][48], split-K=8, then reduce
        sgemm_xp<<<dim3(1, MTOT / 64, 8), 256, 0, stream>>>(
            xzT, cw, cb, xp_w, partX, MTOT * 48);
        k_kred<8><<<(MTOT * 48 / 4 + 511) / 512, 512, 0, stream>>>(
            partX, xdbl, MTOT * 48 / 4);

        // scan (fused conv + dt_proj + epilogue) -> yT
        k_scan11<<<dim3(DINNER, BATCH), 256, 0, stream>>>(
            xdbl, xzT, dtp_w, dtp_b, cw, cb, Al, Dsk, yT);

        if (i < NLAYERS - 1) {
            // out_proj: 64x32 tile, split-K=2 -> 1024 blocks (4/CU), TN=2
            sgemm3<64, 32, 16, 4, 2, true, DINNER, 2, false>
                <<<dim3(DMODEL / 32, MTOT / 64, 2), 256, 0, stream>>>(
                    yT, MTOT, o_w, o_w, DINNER, partO, DMODEL, MTOT * DMODEL);
        } else {
            k_wsum<<<1, DINNER, 0, stream>>>(o_w, wsum);
            k_finalT<<<MTOT / 32, 256, 0, stream>>>(yT, wsum, out);
        }
    }
}